// Round 11
// baseline (490.586 us; speedup 1.0000x reference)
//
#include <hip/hip_runtime.h>
#include <math.h>

// ---------------------------------------------------------------------------
// HGT layer slice. R11: nr_gemm v2 (R10 post-mortem: epilogue = 64 scattered
// 2-byte stores/lane -> 1.95 TB/s, 24% HBM; A refetched per rel).
//   - A fragments loaded once into registers, all 8 rels looped in-block
//   - epilogue: wave-private LDS [32][136] f16 transpose, then 8 coalesced
//     half8 (16 B) stores per lane (256 B contiguous per quad-row)
//   - U and VM gemms combined in one launch (grid.y=2) for CU balance
//
// attend v2.1 (R9-proven), score path fp32 (R6), parallel scan (R10).
// Pipeline: init -> convert -> hconv -> hist -> offsets -> scanA/B/C ->
// scatter -> kq_f32 -> vproj(MFMA) -> nr_gemm2 -> attend -> out(MFMA).
// ---------------------------------------------------------------------------

#define N_NODES 50000
#define N_EDGES 500000
#define DIM 128
#define TT 8
#define RR 8
#define RSQRT_DK 0.08838834764831845f

#define CHUNK_GRID 399               // 399*128 = 51072 >= 50000 + 8*127
#define NODE_LIST_LEN (CHUNK_GRID * 128)
#define GRID_E ((N_EDGES + 255) / 256)   // 1954, also covers N
#define GEMM_ROWBLKS ((N_NODES + 127) / 128)  // 391
#define SCAN_BLOCKS ((N_NODES + 255) / 256)   // 196

// word offsets (4B units); _Float16 index = 2*word
#define OFF_U 0
#define OFF_HF 0                   // alias: hF16 [n][128] (dead before U write)
#define OFF_VM 25600000
#define OFF_QF 25600000            // alias: qF16 (dead before VM write)
#define OFF_KF 51200000
#define OFF_AGGF 54400000
#define OFF_VF 54400000            // alias: vF16 (dead before attend writes agg)
#define OFF_ATTF 57600000          // 65,536 words each, 100k spacing
#define OFF_MSGT 57700000
#define OFF_WVT 57800000
#define OFF_WAT 57900000
#define OFF_INT 58000000           // int region, +701,872 -> 58,701,872 words
#define IO_NLIST 0                 // 51,072
#define IO_CNT_N 51072
#define IO_CUR_N 51080
#define IO_POFF_N 51088
#define IO_DCNT 51104              // 50,000
#define IO_DCUR 101104             // 50,000
#define IO_DOFF 151104             // 50,000
#define IO_DPR 201104              // 500,000 packed (src*8|rel) per CSR slot
#define IO_BLKSUM 701104           // 256 per-scan-block totals
#define IO_BLKOFF 701360           // 256 scanned block offsets; end 701,616

typedef _Float16 half8 __attribute__((ext_vector_type(8)));
typedef _Float16 half4 __attribute__((ext_vector_type(4)));
typedef float f32x4 __attribute__((ext_vector_type(4)));

__global__ void init_kernel(int* wsi) {
    int i = blockIdx.x * blockDim.x + threadIdx.x;
    if (i < NODE_LIST_LEN) wsi[IO_NLIST + i] = -1;
    if (i < 32) wsi[IO_CNT_N + i] = 0;
    if (i < 100000) wsi[IO_DCNT + i] = 0;  // dcnt + dcur contiguous
}

// attF straight [r][d][f]; msgT/WvT/WaT transposed to [.][f][d], all f16
__global__ void convert_kernel(const float* __restrict__ att,
                               const float* __restrict__ msg,
                               const float* __restrict__ Wv,
                               const float* __restrict__ Wa,
                               _Float16* __restrict__ attF,
                               _Float16* __restrict__ msgT,
                               _Float16* __restrict__ WvT,
                               _Float16* __restrict__ WaT) {
    int i = blockIdx.x * 256 + threadIdx.x;
    if (i >= RR * DIM * DIM) return;
    int td = i >> 14, d = (i >> 7) & 127, f = i & 127;
    int tr = (td << 14) + (f << 7) + d;
    attF[i] = (_Float16)att[i];
    msgT[tr] = (_Float16)msg[i];
    WvT[tr] = (_Float16)Wv[i];
    WaT[tr] = (_Float16)Wa[i];
}

__global__ void hconv_kernel(const float* __restrict__ h,
                             _Float16* __restrict__ hF) {
    int i = blockIdx.x * 256 + threadIdx.x;
    if (i < N_NODES * DIM / 4) {
        float4 v = ((const float4*)h)[i];
        half4 o;
        o[0] = (_Float16)v.x; o[1] = (_Float16)v.y;
        o[2] = (_Float16)v.z; o[3] = (_Float16)v.w;
        *(half4*)(hF + (size_t)i * 4) = o;
    }
}

__global__ void hist_kernel(const int* __restrict__ ntype,
                            const int* __restrict__ adj, int* wsi) {
    __shared__ int cn[TT];
    int tid = threadIdx.x;
    if (tid < TT) cn[tid] = 0;
    __syncthreads();
    int i = blockIdx.x * blockDim.x + tid;
    if (i < N_NODES) atomicAdd(&cn[ntype[i]], 1);
    if (i < N_EDGES) atomicAdd(&wsi[IO_DCNT + adj[N_EDGES + i]], 1);
    __syncthreads();
    if (tid < TT && cn[tid] > 0) atomicAdd(&wsi[IO_CNT_N + tid], cn[tid]);
}

__global__ void offsets_kernel(int* wsi) {
    int off = 0;
    for (int t = 0; t < TT; ++t) {
        wsi[IO_POFF_N + t] = off;
        off += ((wsi[IO_CNT_N + t] + 127) >> 7) << 7;  // pad to 128
    }
}

// 3-phase parallel exclusive scan of the 50k dst counts
__global__ __launch_bounds__(256) void scanA_kernel(int* wsi) {
    __shared__ int tmp[256];
    int tid = threadIdx.x;
    int i = blockIdx.x * 256 + tid;
    int v = (i < N_NODES) ? wsi[IO_DCNT + i] : 0;
    tmp[tid] = v;
    __syncthreads();
    for (int off = 1; off < 256; off <<= 1) {
        int t = (tid >= off) ? tmp[tid - off] : 0;
        __syncthreads();
        tmp[tid] += t;
        __syncthreads();
    }
    if (i < N_NODES) wsi[IO_DOFF + i] = tmp[tid] - v;  // block-local exclusive
    if (tid == 255) wsi[IO_BLKSUM + blockIdx.x] = tmp[255];
}

__global__ __launch_bounds__(256) void scanB_kernel(int* wsi) {
    __shared__ int tmp[256];
    int tid = threadIdx.x;
    int v = (tid < SCAN_BLOCKS) ? wsi[IO_BLKSUM + tid] : 0;
    tmp[tid] = v;
    __syncthreads();
    for (int off = 1; off < 256; off <<= 1) {
        int t = (tid >= off) ? tmp[tid - off] : 0;
        __syncthreads();
        tmp[tid] += t;
        __syncthreads();
    }
    wsi[IO_BLKOFF + tid] = tmp[tid] - v;
}

__global__ __launch_bounds__(256) void scanC_kernel(int* wsi) {
    int i = blockIdx.x * 256 + threadIdx.x;
    if (i < N_NODES) wsi[IO_DOFF + i] += wsi[IO_BLKOFF + blockIdx.x];
}

__global__ void scatter_kernel(const int* __restrict__ ntype,
                               const int* __restrict__ etype,
                               const int* __restrict__ adj, int* wsi) {
    __shared__ int cn[TT], bn[TT];
    int tid = threadIdx.x;
    if (tid < TT) cn[tid] = 0;
    __syncthreads();
    int i = blockIdx.x * blockDim.x + tid;
    int t = -1, rnk = 0;
    if (i < N_NODES) {
        t = ntype[i];
        rnk = atomicAdd(&cn[t], 1);
    }
    __syncthreads();
    if (tid < TT && cn[tid] > 0) bn[tid] = atomicAdd(&wsi[IO_CUR_N + tid], cn[tid]);
    __syncthreads();
    if (t >= 0)
        wsi[IO_NLIST + wsi[IO_POFF_N + t] + bn[t] + rnk] = i;
    if (i < N_EDGES) {
        int d = adj[N_EDGES + i];
        int pos = wsi[IO_DOFF + d] + atomicAdd(&wsi[IO_DCUR + d], 1);
        wsi[IO_DPR + pos] = (adj[i] << 3) | etype[i];  // packed src*8|rel
    }
}

// k,q: fp32 vector tile GEMM (score path is argmax-sensitive; R6 post-mortem)
__global__ __launch_bounds__(256) void kq_f32_kernel(
    const float* __restrict__ h, const int* __restrict__ ntype,
    const float* __restrict__ Wk, const float* __restrict__ Wq,
    const int* __restrict__ nlist, _Float16* __restrict__ kout,
    _Float16* __restrict__ qout) {
    __shared__ float hl[32][DIM + 4];
    __shared__ int nid[32];
    int tid = threadIdx.x;
    int base = blockIdx.x * 32;
    if (tid < 32) nid[tid] = nlist[base + tid];
    __syncthreads();
    if (nid[0] < 0) return;
    int t = ntype[nid[0]];

    for (int r2 = 0; r2 < 32; r2 += 2) {
        int row = r2 + (tid >> 7);
        int col = tid & 127;
        int n = nid[row];
        if (n < 0) n = 0;
        hl[row][col] = h[(size_t)n * DIM + col];
    }
    __syncthreads();
    int te = tid >> 5, tc = tid & 31;

#pragma unroll
    for (int w = 0; w < 2; ++w) {
        const float* W = (w == 0 ? Wk : Wq) + (size_t)t * DIM * DIM;
        const float4* W4 = (const float4*)W;
        _Float16* O = (w == 0 ? kout : qout);
        float acc[4][4] = {};
        for (int i = 0; i < DIM; ++i) {
            float4 a = W4[i * 32 + tc];
#pragma unroll
            for (int j = 0; j < 4; ++j) {
                float hv = hl[te * 4 + j][i];
                acc[j][0] += hv * a.x;
                acc[j][1] += hv * a.y;
                acc[j][2] += hv * a.z;
                acc[j][3] += hv * a.w;
            }
        }
#pragma unroll
        for (int j = 0; j < 4; ++j) {
            int n = nid[te * 4 + j];
            if (n >= 0) {
                half4 o;
                o[0] = (_Float16)acc[j][0];
                o[1] = (_Float16)acc[j][1];
                o[2] = (_Float16)acc[j][2];
                o[3] = (_Float16)acc[j][3];
                *(half4*)(O + (size_t)n * DIM + tc * 4) = o;
            }
        }
    }
}

// v: 128-node type-uniform chunk MFMA GEMM (value path: f16-tolerant)
__global__ __launch_bounds__(256) void vproj_kernel(
    const _Float16* __restrict__ hF, const int* __restrict__ ntype,
    const _Float16* __restrict__ WvT, const int* __restrict__ nlist,
    _Float16* __restrict__ vout) {
    __shared__ int nid[128];
    int tid = threadIdx.x;
    if (tid < 128) nid[tid] = nlist[blockIdx.x * 128 + tid];
    __syncthreads();
    if (nid[0] < 0) return;
    int t = ntype[nid[0]];
    int wv = tid >> 6, lane = tid & 63, l16 = lane & 15, quad = lane >> 4;
    int r0 = wv * 32;
    int nA[2];
#pragma unroll
    for (int m = 0; m < 2; ++m) nA[m] = nid[r0 + m * 16 + l16];
    const _Float16* B = WvT + (t << 14);
    f32x4 acc[2][8];
#pragma unroll
    for (int m = 0; m < 2; ++m)
#pragma unroll
        for (int c = 0; c < 8; ++c) acc[m][c] = (f32x4){0.f, 0.f, 0.f, 0.f};
    for (int kk = 0; kk < 4; ++kk) {
        int kb = kk * 32 + quad * 8;
        half8 a[2];
#pragma unroll
        for (int m = 0; m < 2; ++m)
            a[m] = (nA[m] >= 0)
                       ? *(const half8*)(hF + (size_t)nA[m] * DIM + kb)
                       : (half8){0, 0, 0, 0, 0, 0, 0, 0};
#pragma unroll
        for (int c = 0; c < 8; ++c) {
            half8 b = *(const half8*)(B + (c * 16 + l16) * DIM + kb);
#pragma unroll
            for (int m = 0; m < 2; ++m)
                acc[m][c] = __builtin_amdgcn_mfma_f32_16x16x32_f16(
                    a[m], b, acc[m][c], 0, 0, 0);
        }
    }
#pragma unroll
    for (int m = 0; m < 2; ++m)
#pragma unroll
        for (int c = 0; c < 8; ++c)
#pragma unroll
            for (int rg = 0; rg < 4; ++rg) {
                int node = nid[r0 + m * 16 + quad * 4 + rg];
                if (node >= 0)
                    vout[(size_t)node * DIM + c * 16 + l16] =
                        (_Float16)acc[m][c][rg];
            }
}

// ---------------------------------------------------------------------------
// nr_gemm v2: Out[n, rel, :] = scale_r * A[n,:] @ B[rel]^T for all 8 rels.
// blockIdx.y: 0 = U (A=qF, B=attF, scale=pri*rsqrt_dk), 1 = VM (A=vF, B=msgT).
// A fragments register-resident across the rel loop (R10: A refetched 8x).
// Epilogue: stage C-layout into wave-private LDS [32][136] f16 (pad kills
// 272B-stride conflicts), one uniform barrier, then 8 half8 (16B) coalesced
// stores per lane (R10: 64 scattered 2B stores -> 24% HBM efficiency).
// No early returns: tail waves keep the per-rel barrier uniform.
// ---------------------------------------------------------------------------
__global__ __launch_bounds__(256) void nr_gemm2_kernel(
    const _Float16* __restrict__ qF, const _Float16* __restrict__ attF,
    _Float16* __restrict__ UF, const _Float16* __restrict__ vF,
    const _Float16* __restrict__ msgT, _Float16* __restrict__ VMF,
    const float* __restrict__ pri) {
    __shared__ _Float16 stage[4][32][136];
    int which = blockIdx.y;
    const _Float16* A = which ? vF : qF;
    const _Float16* B = which ? msgT : attF;
    _Float16* Of = which ? VMF : UF;
    int tid = threadIdx.x;
    int wv = tid >> 6, lane = tid & 63;
    int l16 = lane & 15, quad = lane >> 4;
    int row0 = blockIdx.x * 128 + wv * 32;

    // A fragments once: afrag[m][kk] covers rows row0+m*16+l16, k=kk*32+quad*8
    half8 afrag[2][4];
#pragma unroll
    for (int m = 0; m < 2; ++m) {
        int node = row0 + m * 16 + l16;
#pragma unroll
        for (int kk = 0; kk < 4; ++kk)
            afrag[m][kk] =
                (node < N_NODES)
                    ? *(const half8*)(A + (size_t)node * DIM + kk * 32 + quad * 8)
                    : (half8){0, 0, 0, 0, 0, 0, 0, 0};
    }

    for (int rel = 0; rel < RR; ++rel) {
        float scale = which ? 1.0f : pri[rel] * RSQRT_DK;
        const _Float16* Bb = B + (rel << 14);
        f32x4 acc[2][8];
#pragma unroll
        for (int m = 0; m < 2; ++m)
#pragma unroll
            for (int c = 0; c < 8; ++c) acc[m][c] = (f32x4){0.f, 0.f, 0.f, 0.f};
        for (int kk = 0; kk < 4; ++kk) {
            int kb = kk * 32 + quad * 8;
#pragma unroll
            for (int c = 0; c < 8; ++c) {
                half8 b = *(const half8*)(Bb + (c * 16 + l16) * DIM + kb);
#pragma unroll
                for (int m = 0; m < 2; ++m)
                    acc[m][c] = __builtin_amdgcn_mfma_f32_16x16x32_f16(
                        afrag[m][kk], b, acc[m][c], 0, 0, 0);
            }
        }
        // stage C-layout -> LDS rows (wave-private region)
#pragma unroll
        for (int m = 0; m < 2; ++m)
#pragma unroll
            for (int c = 0; c < 8; ++c)
#pragma unroll
                for (int rg = 0; rg < 4; ++rg)
                    stage[wv][m * 16 + quad * 4 + rg][c * 16 + l16] =
                        (_Float16)(acc[m][c][rg] * scale);
        __syncthreads();  // uniform: every wave runs all 8 rels
        // coalesced stores: 8 iters x (4 rows x 16 half8-segments)
#pragma unroll
        for (int it = 0; it < 8; ++it) {
            int row = it * 4 + quad;
            int node = row0 + row;
            if (node < N_NODES) {
                half8 v = *(const half8*)&stage[wv][row][l16 * 8];
                *(half8*)(Of + ((size_t)node * RR + rel) * DIM + l16 * 8) = v;
            }
        }
        __syncthreads();  // protect stage reuse across rel iterations
    }
}

// ---------------------------------------------------------------------------
// attend v2.1 (R9-proven): fused score+softmax+aggregate, one wave per dst.
// ---------------------------------------------------------------------------
__global__ __launch_bounds__(256) void attend_kernel(
    const _Float16* __restrict__ kF, const _Float16* __restrict__ UF,
    const _Float16* __restrict__ VMF, const int* __restrict__ dpr,
    const int* __restrict__ doff, const int* __restrict__ dcnt,
    _Float16* __restrict__ aggF) {
    int wv = threadIdx.x >> 6, lane = threadIdx.x & 63;
    int dst = blockIdx.x * 4 + wv;
    if (dst >= N_NODES) return;
    int l16 = lane & 15, g = lane >> 4, l8 = lane & 7;
    int beg = doff[dst], cnt = dcnt[dst];

    float m_own = -3e38f, sum_own = 0.f;
    float s0 = 0.f, s1 = 0.f, s2 = 0.f;
    int p0 = 0, p1 = 0, p2 = 0;

    // phase 1: scores, park (s, pr), lane-owned per-rel max
    for (int j0 = 0; j0 < cnt; j0 += 4) {
        int j = j0 + g;
        bool valid = j < cnt;
        int pr = valid ? dpr[beg + j] : 0;
        int src = pr >> 3, rel = pr & 7;
        half8 kv = *(const half8*)(kF + (size_t)src * DIM + l16 * 8);
        half8 uv =
            *(const half8*)(UF + ((size_t)dst * RR + rel) * DIM + l16 * 8);
        float s = 0.f;
#pragma unroll
        for (int i = 0; i < 8; ++i) s += (float)kv[i] * (float)uv[i];
        s += __shfl_xor(s, 1, 16);
        s += __shfl_xor(s, 2, 16);
        s += __shfl_xor(s, 4, 16);
        s += __shfl_xor(s, 8, 16);
        if (!valid) s = -3e38f;
        int slot = j0 >> 6;            // wave-uniform
        int idx = (j0 >> 2) & 15;      // wave-uniform
        if (l16 == idx) {
            if (slot == 0) { s0 = s; p0 = pr; }
            else if (slot == 1) { s1 = s; p1 = pr; }
            else if (slot == 2) { s2 = s; p2 = pr; }
        }
        if (valid && l8 == rel && s > m_own) m_own = s;
    }
    // merge per-rel max across the 4 groups
    m_own = fmaxf(m_own, __shfl_xor(m_own, 16, 64));
    m_own = fmaxf(m_own, __shfl_xor(m_own, 32, 64));

    // phase 2: ex = valid ? exp(s - m[rel]) : 0; park ex; lane-owned sum
    for (int j0 = 0; j0 < cnt; j0 += 4) {
        int j = j0 + g;
        bool valid = j < cnt;
        int slot = j0 >> 6;
        int idx = (j0 >> 2) & 15;
        float s;
        int pr;
        if (slot < 3) {
            float sv = (slot == 0) ? s0 : (slot == 1) ? s1 : s2;
            int pv = (slot == 0) ? p0 : (slot == 1) ? p1 : p2;
            s = __shfl(sv, idx, 16);
            pr = __shfl(pv, idx, 16);
        } else {  // overflow fallback: recompute (cnt>192 ~ never at deg~10)
            pr = valid ? dpr[beg + j] : 0;
            int src = pr >> 3, rel = pr & 7;
            half8 kv = *(const half8*)(kF + (size_t)src * DIM + l16 * 8);
            half8 uv =
                *(const half8*)(UF + ((size_t)dst * RR + rel) * DIM + l16 * 8);
            s = 0.f;
#pragma unroll
            for (int i = 0; i < 8; ++i) s += (float)kv[i] * (float)uv[i];
            s += __shfl_xor(s, 1, 16);
            s += __shfl_xor(s, 2, 16);
            s += __shfl_xor(s, 4, 16);
            s += __shfl_xor(s, 8, 16);
        }
        int rel = pr & 7;
        float mr = __shfl(m_own, rel, 8);
        float ex = valid ? __expf(s - mr) : 0.f;  // mask padding edges
        if (l16 == idx) {
            if (slot == 0) s0 = ex;
            else if (slot == 1) s1 = ex;
            else if (slot == 2) s2 = ex;
        }
        if (l8 == rel) sum_own += ex;
    }
    // merge per-rel sums; invert once
    sum_own += __shfl_xor(sum_own, 16, 64);
    sum_own += __shfl_xor(sum_own, 32, 64);
    float inv_own = (sum_own > 0.f) ? 1.f / sum_own : 0.f;

    // phase 3: acc += alpha * VM[src, rel]  (parked ex is already 0 for pads)
    float acc[8] = {0.f, 0.f, 0.f, 0.f, 0.f, 0.f, 0.f, 0.f};
    for (int j0 = 0; j0 < cnt; j0 += 4) {
        int j = j0 + g;
        bool valid = j < cnt;
        int slot = j0 >> 6;
        int idx = (j0 >> 2) & 15;
        float ex;
        int pr;
        if (slot < 3) {
            float sv = (slot == 0) ? s0 : (slot == 1) ? s1 : s2;
            int pv = (slot == 0) ? p0 : (slot == 1) ? p1 : p2;
            ex = __shfl(sv, idx, 16);
            pr = __shfl(pv, idx, 16);
        } else {
            pr = valid ? dpr[beg + j] : 0;
            int src = pr >> 3, rel = pr & 7;
            half8 kv = *(const half8*)(kF + (size_t)src * DIM + l16 * 8);
            half8 uv =
                *(const half8*)(UF + ((size_t)dst * RR + rel) * DIM + l16 * 8);
            float s = 0.f;
#pragma unroll
            for (int i = 0; i < 8; ++i) s += (float)kv[i] * (float)uv[i];
            s += __shfl_xor(s, 1, 16);
            s += __shfl_xor(s, 2, 16);
            s += __shfl_xor(s, 4, 16);
            s += __shfl_xor(s, 8, 16);
            float mr = __shfl(m_own, (pr & 7), 8);
            ex = valid ? __expf(s - mr) : 0.f;
        }
        int rel = pr & 7, src = pr >> 3;
        float alpha = ex * __shfl(inv_own, rel, 8);
        half8 v =
            *(const half8*)(VMF + ((size_t)src * RR + rel) * DIM + l16 * 8);
#pragma unroll
        for (int i = 0; i < 8; ++i) acc[i] += alpha * (float)v[i];
    }
    // merge acc across the 4 groups (each covers the full 128 dims)
#pragma unroll
    for (int i = 0; i < 8; ++i) {
        acc[i] += __shfl_xor(acc[i], 16, 64);
        acc[i] += __shfl_xor(acc[i], 32, 64);
    }
    if (g == 0) {
        half8 o;
#pragma unroll
        for (int i = 0; i < 8; ++i) o[i] = (_Float16)acc[i];
        *(half8*)(aggF + (size_t)dst * DIM + l16 * 8) = o;
    }
}

// out: 128-node type-uniform chunk MFMA GEMM, fp32 stores with sigmoid gate
__global__ __launch_bounds__(256) void out_kernel(
    const _Float16* __restrict__ aggF, const int* __restrict__ ntype,
    const _Float16* __restrict__ WaT, const float* __restrict__ skip,
    const int* __restrict__ nlist, float* __restrict__ out) {
    __shared__ int nid[128];
    int tid = threadIdx.x;
    if (tid < 128) nid[tid] = nlist[blockIdx.x * 128 + tid];
    __syncthreads();
    if (nid[0] < 0) return;
    int t = ntype[nid[0]];
    float sig = 1.f / (1.f + __expf(-skip[t]));
    int wv = tid >> 6, lane = tid & 63, l16 = lane & 15, quad = lane >> 4;
    int r0 = wv * 32;
    int nA[2];
#pragma unroll
    for (int m = 0; m < 2; ++m) nA[m] = nid[r0 + m * 16 + l16];
    const _Float16* B = WaT + (t << 14);
    f32x4 acc[2][8];
#pragma unroll
    for (int m = 0; m < 2; ++m)
#pragma unroll
        for (int c = 0; c < 8; ++c) acc[m][c] = (f32x4){0.f, 0.f, 0.f, 0.f};
    for (int kk = 0; kk < 4; ++kk) {
        int kb = kk * 32 + quad * 8;
        half8 a[2];
#pragma unroll
        for (int m = 0; m < 2; ++m)
            a[m] = (nA[m] >= 0)
                       ? *(const half8*)(aggF + (size_t)nA[m] * DIM + kb)
                       : (half8){0, 0, 0, 0, 0, 0, 0, 0};
#pragma unroll
        for (int c = 0; c < 8; ++c) {
            half8 b = *(const half8*)(B + (c * 16 + l16) * DIM + kb);
#pragma unroll
            for (int m = 0; m < 2; ++m)
                acc[m][c] = __builtin_amdgcn_mfma_f32_16x16x32_f16(
                    a[m], b, acc[m][c], 0, 0, 0);
        }
    }
#pragma unroll
    for (int m = 0; m < 2; ++m)
#pragma unroll
        for (int c = 0; c < 8; ++c)
#pragma unroll
            for (int rg = 0; rg < 4; ++rg) {
                int node = nid[r0 + m * 16 + quad * 4 + rg];
                if (node >= 0)
                    out[(size_t)node * DIM + c * 16 + l16] =
                        acc[m][c][rg] * sig;
            }
}

extern "C" void kernel_launch(void* const* d_in, const int* in_sizes, int n_in,
                              void* d_out, int out_size, void* d_ws,
                              size_t ws_size, hipStream_t stream) {
    const float* h = (const float*)d_in[0];
    const int* adj = (const int*)d_in[1];
    const int* etype = (const int*)d_in[2];
    const int* ntype = (const int*)d_in[3];
    const float* Wk = (const float*)d_in[6];
    const float* Wq = (const float*)d_in[7];
    const float* Wv = (const float*)d_in[8];
    const float* Wa = (const float*)d_in[9];
    const float* pri = (const float*)d_in[10];
    const float* att = (const float*)d_in[11];
    const float* msg = (const float*)d_in[12];
    const float* skip = (const float*)d_in[13];
    float* out = (float*)d_out;

    int* wsi = (int*)d_ws + OFF_INT;
    _Float16* wsh = (_Float16*)d_ws;
    _Float16* UF = wsh + (size_t)OFF_U * 2;
    _Float16* hF = wsh + (size_t)OFF_HF * 2;
    _Float16* VMF = wsh + (size_t)OFF_VM * 2;
    _Float16* qF = wsh + (size_t)OFF_QF * 2;
    _Float16* kF = wsh + (size_t)OFF_KF * 2;
    _Float16* aggF = wsh + (size_t)OFF_AGGF * 2;
    _Float16* vF = wsh + (size_t)OFF_VF * 2;
    _Float16* attF = wsh + (size_t)OFF_ATTF * 2;
    _Float16* msgT = wsh + (size_t)OFF_MSGT * 2;
    _Float16* WvT = wsh + (size_t)OFF_WVT * 2;
    _Float16* WaT = wsh + (size_t)OFF_WAT * 2;

    init_kernel<<<(100000 + 255) / 256, 256, 0, stream>>>(wsi);
    convert_kernel<<<(RR * DIM * DIM + 255) / 256, 256, 0, stream>>>(
        att, msg, Wv, Wa, attF, msgT, WvT, WaT);
    hconv_kernel<<<(N_NODES * DIM / 4 + 255) / 256, 256, 0, stream>>>(h, hF);
    hist_kernel<<<GRID_E, 256, 0, stream>>>(ntype, adj, wsi);
    offsets_kernel<<<1, 1, 0, stream>>>(wsi);
    scanA_kernel<<<SCAN_BLOCKS, 256, 0, stream>>>(wsi);
    scanB_kernel<<<1, 256, 0, stream>>>(wsi);
    scanC_kernel<<<SCAN_BLOCKS, 256, 0, stream>>>(wsi);
    scatter_kernel<<<GRID_E, 256, 0, stream>>>(ntype, etype, adj, wsi);
    kq_f32_kernel<<<CHUNK_GRID * 4, 256, 0, stream>>>(h, ntype, Wk, Wq,
                                                      wsi + IO_NLIST, kF, qF);
    vproj_kernel<<<CHUNK_GRID, 256, 0, stream>>>(hF, ntype, WvT,
                                                 wsi + IO_NLIST, vF);
    {
        dim3 g(GEMM_ROWBLKS, 2);
        nr_gemm2_kernel<<<g, 256, 0, stream>>>(qF, attF, UF, vF, msgT, VMF,
                                               pri);
    }
    attend_kernel<<<(N_NODES + 3) / 4, 256, 0, stream>>>(
        kF, UF, VMF, wsi + IO_DPR, wsi + IO_DOFF, wsi + IO_DCNT, aggF);
    out_kernel<<<CHUNK_GRID, 256, 0, stream>>>(aggF, ntype, WaT, skip,
                                               wsi + IO_NLIST, out);
}

// Round 12
// 449.488 us; speedup vs baseline: 1.0914x; 1.0914x over previous
//
#include <hip/hip_runtime.h>
#include <math.h>

// ---------------------------------------------------------------------------
// HGT layer slice. R12: nr_gemm2 fix (R11 post-mortem: the 2 __syncthreads
// per rel iteration forced vmcnt(0) drains -> 16 serialized store-drains per
// block, 174 us at 7% VALU. Staging is wave-private -> barriers deleted).
// Also U/VM relaid to [rel][node][128] so a wave's 4 quad-rows are 4
// consecutive node rows = 1 KiB contiguous stores.
//
// attend v2.1 (R9), fp32 score path (R6), parallel scan (R10), register-
// resident A + LDS-transpose epilogue (R11, kept).
// ---------------------------------------------------------------------------

#define N_NODES 50000
#define N_EDGES 500000
#define DIM 128
#define TT 8
#define RR 8
#define RSQRT_DK 0.08838834764831845f

#define CHUNK_GRID 399               // 399*128 = 51072 >= 50000 + 8*127
#define NODE_LIST_LEN (CHUNK_GRID * 128)
#define GRID_E ((N_EDGES + 255) / 256)   // 1954, also covers N
#define GEMM_ROWBLKS ((N_NODES + 127) / 128)  // 391
#define SCAN_BLOCKS ((N_NODES + 255) / 256)   // 196

// word offsets (4B units); _Float16 index = 2*word
#define OFF_U 0                    // UF16 [rel][n][128]
#define OFF_HF 0                   // alias: hF16 [n][128] (dead before U write)
#define OFF_VM 25600000            // VMF16 [rel][n][128]
#define OFF_QF 25600000            // alias: qF16 (dead before VM write)
#define OFF_KF 51200000
#define OFF_AGGF 54400000
#define OFF_VF 54400000            // alias: vF16 (dead before attend writes agg)
#define OFF_ATTF 57600000          // 65,536 words each, 100k spacing
#define OFF_MSGT 57700000
#define OFF_WVT 57800000
#define OFF_WAT 57900000
#define OFF_INT 58000000           // int region, +701,872 -> 58,701,872 words
#define IO_NLIST 0                 // 51,072
#define IO_CNT_N 51072
#define IO_CUR_N 51080
#define IO_POFF_N 51088
#define IO_DCNT 51104              // 50,000
#define IO_DCUR 101104             // 50,000
#define IO_DOFF 151104             // 50,000
#define IO_DPR 201104              // 500,000 packed (src*8|rel) per CSR slot
#define IO_BLKSUM 701104           // 256 per-scan-block totals
#define IO_BLKOFF 701360           // 256 scanned block offsets; end 701,616

typedef _Float16 half8 __attribute__((ext_vector_type(8)));
typedef _Float16 half4 __attribute__((ext_vector_type(4)));
typedef float f32x4 __attribute__((ext_vector_type(4)));

__global__ void init_kernel(int* wsi) {
    int i = blockIdx.x * blockDim.x + threadIdx.x;
    if (i < NODE_LIST_LEN) wsi[IO_NLIST + i] = -1;
    if (i < 32) wsi[IO_CNT_N + i] = 0;
    if (i < 100000) wsi[IO_DCNT + i] = 0;  // dcnt + dcur contiguous
}

// attF straight [r][d][f]; msgT/WvT/WaT transposed to [.][f][d], all f16
__global__ void convert_kernel(const float* __restrict__ att,
                               const float* __restrict__ msg,
                               const float* __restrict__ Wv,
                               const float* __restrict__ Wa,
                               _Float16* __restrict__ attF,
                               _Float16* __restrict__ msgT,
                               _Float16* __restrict__ WvT,
                               _Float16* __restrict__ WaT) {
    int i = blockIdx.x * 256 + threadIdx.x;
    if (i >= RR * DIM * DIM) return;
    int td = i >> 14, d = (i >> 7) & 127, f = i & 127;
    int tr = (td << 14) + (f << 7) + d;
    attF[i] = (_Float16)att[i];
    msgT[tr] = (_Float16)msg[i];
    WvT[tr] = (_Float16)Wv[i];
    WaT[tr] = (_Float16)Wa[i];
}

__global__ void hconv_kernel(const float* __restrict__ h,
                             _Float16* __restrict__ hF) {
    int i = blockIdx.x * 256 + threadIdx.x;
    if (i < N_NODES * DIM / 4) {
        float4 v = ((const float4*)h)[i];
        half4 o;
        o[0] = (_Float16)v.x; o[1] = (_Float16)v.y;
        o[2] = (_Float16)v.z; o[3] = (_Float16)v.w;
        *(half4*)(hF + (size_t)i * 4) = o;
    }
}

__global__ void hist_kernel(const int* __restrict__ ntype,
                            const int* __restrict__ adj, int* wsi) {
    __shared__ int cn[TT];
    int tid = threadIdx.x;
    if (tid < TT) cn[tid] = 0;
    __syncthreads();
    int i = blockIdx.x * blockDim.x + tid;
    if (i < N_NODES) atomicAdd(&cn[ntype[i]], 1);
    if (i < N_EDGES) atomicAdd(&wsi[IO_DCNT + adj[N_EDGES + i]], 1);
    __syncthreads();
    if (tid < TT && cn[tid] > 0) atomicAdd(&wsi[IO_CNT_N + tid], cn[tid]);
}

__global__ void offsets_kernel(int* wsi) {
    int off = 0;
    for (int t = 0; t < TT; ++t) {
        wsi[IO_POFF_N + t] = off;
        off += ((wsi[IO_CNT_N + t] + 127) >> 7) << 7;  // pad to 128
    }
}

// 3-phase parallel exclusive scan of the 50k dst counts
__global__ __launch_bounds__(256) void scanA_kernel(int* wsi) {
    __shared__ int tmp[256];
    int tid = threadIdx.x;
    int i = blockIdx.x * 256 + tid;
    int v = (i < N_NODES) ? wsi[IO_DCNT + i] : 0;
    tmp[tid] = v;
    __syncthreads();
    for (int off = 1; off < 256; off <<= 1) {
        int t = (tid >= off) ? tmp[tid - off] : 0;
        __syncthreads();
        tmp[tid] += t;
        __syncthreads();
    }
    if (i < N_NODES) wsi[IO_DOFF + i] = tmp[tid] - v;  // block-local exclusive
    if (tid == 255) wsi[IO_BLKSUM + blockIdx.x] = tmp[255];
}

__global__ __launch_bounds__(256) void scanB_kernel(int* wsi) {
    __shared__ int tmp[256];
    int tid = threadIdx.x;
    int v = (tid < SCAN_BLOCKS) ? wsi[IO_BLKSUM + tid] : 0;
    tmp[tid] = v;
    __syncthreads();
    for (int off = 1; off < 256; off <<= 1) {
        int t = (tid >= off) ? tmp[tid - off] : 0;
        __syncthreads();
        tmp[tid] += t;
        __syncthreads();
    }
    wsi[IO_BLKOFF + tid] = tmp[tid] - v;
}

__global__ __launch_bounds__(256) void scanC_kernel(int* wsi) {
    int i = blockIdx.x * 256 + threadIdx.x;
    if (i < N_NODES) wsi[IO_DOFF + i] += wsi[IO_BLKOFF + blockIdx.x];
}

__global__ void scatter_kernel(const int* __restrict__ ntype,
                               const int* __restrict__ etype,
                               const int* __restrict__ adj, int* wsi) {
    __shared__ int cn[TT], bn[TT];
    int tid = threadIdx.x;
    if (tid < TT) cn[tid] = 0;
    __syncthreads();
    int i = blockIdx.x * blockDim.x + tid;
    int t = -1, rnk = 0;
    if (i < N_NODES) {
        t = ntype[i];
        rnk = atomicAdd(&cn[t], 1);
    }
    __syncthreads();
    if (tid < TT && cn[tid] > 0) bn[tid] = atomicAdd(&wsi[IO_CUR_N + tid], cn[tid]);
    __syncthreads();
    if (t >= 0)
        wsi[IO_NLIST + wsi[IO_POFF_N + t] + bn[t] + rnk] = i;
    if (i < N_EDGES) {
        int d = adj[N_EDGES + i];
        int pos = wsi[IO_DOFF + d] + atomicAdd(&wsi[IO_DCUR + d], 1);
        wsi[IO_DPR + pos] = (adj[i] << 3) | etype[i];  // packed src*8|rel
    }
}

// k,q: fp32 vector tile GEMM (score path is argmax-sensitive; R6 post-mortem)
__global__ __launch_bounds__(256) void kq_f32_kernel(
    const float* __restrict__ h, const int* __restrict__ ntype,
    const float* __restrict__ Wk, const float* __restrict__ Wq,
    const int* __restrict__ nlist, _Float16* __restrict__ kout,
    _Float16* __restrict__ qout) {
    __shared__ float hl[32][DIM + 4];
    __shared__ int nid[32];
    int tid = threadIdx.x;
    int base = blockIdx.x * 32;
    if (tid < 32) nid[tid] = nlist[base + tid];
    __syncthreads();
    if (nid[0] < 0) return;
    int t = ntype[nid[0]];

    for (int r2 = 0; r2 < 32; r2 += 2) {
        int row = r2 + (tid >> 7);
        int col = tid & 127;
        int n = nid[row];
        if (n < 0) n = 0;
        hl[row][col] = h[(size_t)n * DIM + col];
    }
    __syncthreads();
    int te = tid >> 5, tc = tid & 31;

#pragma unroll
    for (int w = 0; w < 2; ++w) {
        const float* W = (w == 0 ? Wk : Wq) + (size_t)t * DIM * DIM;
        const float4* W4 = (const float4*)W;
        _Float16* O = (w == 0 ? kout : qout);
        float acc[4][4] = {};
        for (int i = 0; i < DIM; ++i) {
            float4 a = W4[i * 32 + tc];
#pragma unroll
            for (int j = 0; j < 4; ++j) {
                float hv = hl[te * 4 + j][i];
                acc[j][0] += hv * a.x;
                acc[j][1] += hv * a.y;
                acc[j][2] += hv * a.z;
                acc[j][3] += hv * a.w;
            }
        }
#pragma unroll
        for (int j = 0; j < 4; ++j) {
            int n = nid[te * 4 + j];
            if (n >= 0) {
                half4 o;
                o[0] = (_Float16)acc[j][0];
                o[1] = (_Float16)acc[j][1];
                o[2] = (_Float16)acc[j][2];
                o[3] = (_Float16)acc[j][3];
                *(half4*)(O + (size_t)n * DIM + tc * 4) = o;
            }
        }
    }
}

// v: 128-node type-uniform chunk MFMA GEMM (value path: f16-tolerant)
__global__ __launch_bounds__(256) void vproj_kernel(
    const _Float16* __restrict__ hF, const int* __restrict__ ntype,
    const _Float16* __restrict__ WvT, const int* __restrict__ nlist,
    _Float16* __restrict__ vout) {
    __shared__ int nid[128];
    int tid = threadIdx.x;
    if (tid < 128) nid[tid] = nlist[blockIdx.x * 128 + tid];
    __syncthreads();
    if (nid[0] < 0) return;
    int t = ntype[nid[0]];
    int wv = tid >> 6, lane = tid & 63, l16 = lane & 15, quad = lane >> 4;
    int r0 = wv * 32;
    int nA[2];
#pragma unroll
    for (int m = 0; m < 2; ++m) nA[m] = nid[r0 + m * 16 + l16];
    const _Float16* B = WvT + (t << 14);
    f32x4 acc[2][8];
#pragma unroll
    for (int m = 0; m < 2; ++m)
#pragma unroll
        for (int c = 0; c < 8; ++c) acc[m][c] = (f32x4){0.f, 0.f, 0.f, 0.f};
    for (int kk = 0; kk < 4; ++kk) {
        int kb = kk * 32 + quad * 8;
        half8 a[2];
#pragma unroll
        for (int m = 0; m < 2; ++m)
            a[m] = (nA[m] >= 0)
                       ? *(const half8*)(hF + (size_t)nA[m] * DIM + kb)
                       : (half8){0, 0, 0, 0, 0, 0, 0, 0};
#pragma unroll
        for (int c = 0; c < 8; ++c) {
            half8 b = *(const half8*)(B + (c * 16 + l16) * DIM + kb);
#pragma unroll
            for (int m = 0; m < 2; ++m)
                acc[m][c] = __builtin_amdgcn_mfma_f32_16x16x32_f16(
                    a[m], b, acc[m][c], 0, 0, 0);
        }
    }
#pragma unroll
    for (int m = 0; m < 2; ++m)
#pragma unroll
        for (int c = 0; c < 8; ++c)
#pragma unroll
            for (int rg = 0; rg < 4; ++rg) {
                int node = nid[r0 + m * 16 + quad * 4 + rg];
                if (node >= 0)
                    vout[(size_t)node * DIM + c * 16 + l16] =
                        (_Float16)acc[m][c][rg];
            }
}

// ---------------------------------------------------------------------------
// nr_gemm v3: Out[rel][n][:] = scale_r * A[n,:] @ B[rel]^T for all 8 rels.
// blockIdx.y: 0 = U (A=qF, B=attF), 1 = VM (A=vF, B=msgT).
// A register-resident (R11); LDS transpose epilogue is WAVE-PRIVATE -> NO
// barriers (R11 regression: __syncthreads forced vmcnt(0) drain per rel).
// [rel][node] layout: a wave's 4 quad-rows are consecutive nodes = 1 KiB
// contiguous store per iteration.
// ---------------------------------------------------------------------------
__global__ __launch_bounds__(256) void nr_gemm2_kernel(
    const _Float16* __restrict__ qF, const _Float16* __restrict__ attF,
    _Float16* __restrict__ UF, const _Float16* __restrict__ vF,
    const _Float16* __restrict__ msgT, _Float16* __restrict__ VMF,
    const float* __restrict__ pri) {
    __shared__ _Float16 stage[4][32][136];
    int which = blockIdx.y;
    const _Float16* A = which ? vF : qF;
    const _Float16* B = which ? msgT : attF;
    _Float16* Of = which ? VMF : UF;
    int tid = threadIdx.x;
    int wv = tid >> 6, lane = tid & 63;
    int l16 = lane & 15, quad = lane >> 4;
    int row0 = blockIdx.x * 128 + wv * 32;

    // A fragments once: afrag[m][kk] covers rows row0+m*16+l16, k=kk*32+quad*8
    half8 afrag[2][4];
#pragma unroll
    for (int m = 0; m < 2; ++m) {
        int node = row0 + m * 16 + l16;
#pragma unroll
        for (int kk = 0; kk < 4; ++kk)
            afrag[m][kk] =
                (node < N_NODES)
                    ? *(const half8*)(A + (size_t)node * DIM + kk * 32 + quad * 8)
                    : (half8){0, 0, 0, 0, 0, 0, 0, 0};
    }

    for (int rel = 0; rel < RR; ++rel) {
        float scale = which ? 1.0f : pri[rel] * RSQRT_DK;
        const _Float16* Bb = B + (rel << 14);
        f32x4 acc[2][8];
#pragma unroll
        for (int m = 0; m < 2; ++m)
#pragma unroll
            for (int c = 0; c < 8; ++c) acc[m][c] = (f32x4){0.f, 0.f, 0.f, 0.f};
        for (int kk = 0; kk < 4; ++kk) {
            int kb = kk * 32 + quad * 8;
#pragma unroll
            for (int c = 0; c < 8; ++c) {
                half8 b = *(const half8*)(Bb + (c * 16 + l16) * DIM + kb);
#pragma unroll
                for (int m = 0; m < 2; ++m)
                    acc[m][c] = __builtin_amdgcn_mfma_f32_16x16x32_f16(
                        afrag[m][kk], b, acc[m][c], 0, 0, 0);
            }
        }
        // stage C-layout -> wave-private LDS rows (no barrier: same wave
        // writes and reads its own region; lgkmcnt orders it)
#pragma unroll
        for (int m = 0; m < 2; ++m)
#pragma unroll
            for (int c = 0; c < 8; ++c)
#pragma unroll
                for (int rg = 0; rg < 4; ++rg)
                    stage[wv][m * 16 + quad * 4 + rg][c * 16 + l16] =
                        (_Float16)(acc[m][c][rg] * scale);
        // coalesced stores: [rel][node] layout -> 4 consecutive node rows
        // per iteration = 64 lanes x 16B = 1 KiB contiguous
        _Float16* Orel = Of + ((size_t)rel * N_NODES + row0) * DIM;
#pragma unroll
        for (int it = 0; it < 8; ++it) {
            int row = it * 4 + quad;
            if (row0 + row < N_NODES) {
                half8 v = *(const half8*)&stage[wv][row][l16 * 8];
                *(half8*)(Orel + (size_t)row * DIM + l16 * 8) = v;
            }
        }
    }
}

// ---------------------------------------------------------------------------
// attend v2.1 (R9-proven); U/VM indexed [rel][node][128] (R12 relayout).
// ---------------------------------------------------------------------------
__global__ __launch_bounds__(256) void attend_kernel(
    const _Float16* __restrict__ kF, const _Float16* __restrict__ UF,
    const _Float16* __restrict__ VMF, const int* __restrict__ dpr,
    const int* __restrict__ doff, const int* __restrict__ dcnt,
    _Float16* __restrict__ aggF) {
    int wv = threadIdx.x >> 6, lane = threadIdx.x & 63;
    int dst = blockIdx.x * 4 + wv;
    if (dst >= N_NODES) return;
    int l16 = lane & 15, g = lane >> 4, l8 = lane & 7;
    int beg = doff[dst], cnt = dcnt[dst];

    float m_own = -3e38f, sum_own = 0.f;
    float s0 = 0.f, s1 = 0.f, s2 = 0.f;
    int p0 = 0, p1 = 0, p2 = 0;

    // phase 1: scores, park (s, pr), lane-owned per-rel max
    for (int j0 = 0; j0 < cnt; j0 += 4) {
        int j = j0 + g;
        bool valid = j < cnt;
        int pr = valid ? dpr[beg + j] : 0;
        int src = pr >> 3, rel = pr & 7;
        half8 kv = *(const half8*)(kF + (size_t)src * DIM + l16 * 8);
        half8 uv = *(const half8*)(UF + ((size_t)rel * N_NODES + dst) * DIM +
                                   l16 * 8);
        float s = 0.f;
#pragma unroll
        for (int i = 0; i < 8; ++i) s += (float)kv[i] * (float)uv[i];
        s += __shfl_xor(s, 1, 16);
        s += __shfl_xor(s, 2, 16);
        s += __shfl_xor(s, 4, 16);
        s += __shfl_xor(s, 8, 16);
        if (!valid) s = -3e38f;
        int slot = j0 >> 6;            // wave-uniform
        int idx = (j0 >> 2) & 15;      // wave-uniform
        if (l16 == idx) {
            if (slot == 0) { s0 = s; p0 = pr; }
            else if (slot == 1) { s1 = s; p1 = pr; }
            else if (slot == 2) { s2 = s; p2 = pr; }
        }
        if (valid && l8 == rel && s > m_own) m_own = s;
    }
    // merge per-rel max across the 4 groups
    m_own = fmaxf(m_own, __shfl_xor(m_own, 16, 64));
    m_own = fmaxf(m_own, __shfl_xor(m_own, 32, 64));

    // phase 2: ex = valid ? exp(s - m[rel]) : 0; park ex; lane-owned sum
    for (int j0 = 0; j0 < cnt; j0 += 4) {
        int j = j0 + g;
        bool valid = j < cnt;
        int slot = j0 >> 6;
        int idx = (j0 >> 2) & 15;
        float s;
        int pr;
        if (slot < 3) {
            float sv = (slot == 0) ? s0 : (slot == 1) ? s1 : s2;
            int pv = (slot == 0) ? p0 : (slot == 1) ? p1 : p2;
            s = __shfl(sv, idx, 16);
            pr = __shfl(pv, idx, 16);
        } else {  // overflow fallback: recompute (cnt>192 ~ never at deg~10)
            pr = valid ? dpr[beg + j] : 0;
            int src = pr >> 3, rel = pr & 7;
            half8 kv = *(const half8*)(kF + (size_t)src * DIM + l16 * 8);
            half8 uv = *(const half8*)(UF +
                                       ((size_t)rel * N_NODES + dst) * DIM +
                                       l16 * 8);
            s = 0.f;
#pragma unroll
            for (int i = 0; i < 8; ++i) s += (float)kv[i] * (float)uv[i];
            s += __shfl_xor(s, 1, 16);
            s += __shfl_xor(s, 2, 16);
            s += __shfl_xor(s, 4, 16);
            s += __shfl_xor(s, 8, 16);
        }
        int rel = pr & 7;
        float mr = __shfl(m_own, rel, 8);
        float ex = valid ? __expf(s - mr) : 0.f;  // mask padding edges
        if (l16 == idx) {
            if (slot == 0) s0 = ex;
            else if (slot == 1) s1 = ex;
            else if (slot == 2) s2 = ex;
        }
        if (l8 == rel) sum_own += ex;
    }
    // merge per-rel sums; invert once
    sum_own += __shfl_xor(sum_own, 16, 64);
    sum_own += __shfl_xor(sum_own, 32, 64);
    float inv_own = (sum_own > 0.f) ? 1.f / sum_own : 0.f;

    // phase 3: acc += alpha * VM[rel][src]  (parked ex is already 0 for pads)
    float acc[8] = {0.f, 0.f, 0.f, 0.f, 0.f, 0.f, 0.f, 0.f};
    for (int j0 = 0; j0 < cnt; j0 += 4) {
        int j = j0 + g;
        bool valid = j < cnt;
        int slot = j0 >> 6;
        int idx = (j0 >> 2) & 15;
        float ex;
        int pr;
        if (slot < 3) {
            float sv = (slot == 0) ? s0 : (slot == 1) ? s1 : s2;
            int pv = (slot == 0) ? p0 : (slot == 1) ? p1 : p2;
            ex = __shfl(sv, idx, 16);
            pr = __shfl(pv, idx, 16);
        } else {
            pr = valid ? dpr[beg + j] : 0;
            int src = pr >> 3, rel = pr & 7;
            half8 kv = *(const half8*)(kF + (size_t)src * DIM + l16 * 8);
            half8 uv = *(const half8*)(UF +
                                       ((size_t)rel * N_NODES + dst) * DIM +
                                       l16 * 8);
            float s = 0.f;
#pragma unroll
            for (int i = 0; i < 8; ++i) s += (float)kv[i] * (float)uv[i];
            s += __shfl_xor(s, 1, 16);
            s += __shfl_xor(s, 2, 16);
            s += __shfl_xor(s, 4, 16);
            s += __shfl_xor(s, 8, 16);
            float mr = __shfl(m_own, (pr & 7), 8);
            ex = valid ? __expf(s - mr) : 0.f;
        }
        int rel = pr & 7, src = pr >> 3;
        float alpha = ex * __shfl(inv_own, rel, 8);
        half8 v = *(const half8*)(VMF + ((size_t)rel * N_NODES + src) * DIM +
                                  l16 * 8);
#pragma unroll
        for (int i = 0; i < 8; ++i) acc[i] += alpha * (float)v[i];
    }
    // merge acc across the 4 groups (each covers the full 128 dims)
#pragma unroll
    for (int i = 0; i < 8; ++i) {
        acc[i] += __shfl_xor(acc[i], 16, 64);
        acc[i] += __shfl_xor(acc[i], 32, 64);
    }
    if (g == 0) {
        half8 o;
#pragma unroll
        for (int i = 0; i < 8; ++i) o[i] = (_Float16)acc[i];
        *(half8*)(aggF + (size_t)dst * DIM + l16 * 8) = o;
    }
}

// out: 128-node type-uniform chunk MFMA GEMM, fp32 stores with sigmoid gate
__global__ __launch_bounds__(256) void out_kernel(
    const _Float16* __restrict__ aggF, const int* __restrict__ ntype,
    const _Float16* __restrict__ WaT, const float* __restrict__ skip,
    const int* __restrict__ nlist, float* __restrict__ out) {
    __shared__ int nid[128];
    int tid = threadIdx.x;
    if (tid < 128) nid[tid] = nlist[blockIdx.x * 128 + tid];
    __syncthreads();
    if (nid[0] < 0) return;
    int t = ntype[nid[0]];
    float sig = 1.f / (1.f + __expf(-skip[t]));
    int wv = tid >> 6, lane = tid & 63, l16 = lane & 15, quad = lane >> 4;
    int r0 = wv * 32;
    int nA[2];
#pragma unroll
    for (int m = 0; m < 2; ++m) nA[m] = nid[r0 + m * 16 + l16];
    const _Float16* B = WaT + (t << 14);
    f32x4 acc[2][8];
#pragma unroll
    for (int m = 0; m < 2; ++m)
#pragma unroll
        for (int c = 0; c < 8; ++c) acc[m][c] = (f32x4){0.f, 0.f, 0.f, 0.f};
    for (int kk = 0; kk < 4; ++kk) {
        int kb = kk * 32 + quad * 8;
        half8 a[2];
#pragma unroll
        for (int m = 0; m < 2; ++m)
            a[m] = (nA[m] >= 0)
                       ? *(const half8*)(aggF + (size_t)nA[m] * DIM + kb)
                       : (half8){0, 0, 0, 0, 0, 0, 0, 0};
#pragma unroll
        for (int c = 0; c < 8; ++c) {
            half8 b = *(const half8*)(B + (c * 16 + l16) * DIM + kb);
#pragma unroll
            for (int m = 0; m < 2; ++m)
                acc[m][c] = __builtin_amdgcn_mfma_f32_16x16x32_f16(
                    a[m], b, acc[m][c], 0, 0, 0);
        }
    }
#pragma unroll
    for (int m = 0; m < 2; ++m)
#pragma unroll
        for (int c = 0; c < 8; ++c)
#pragma unroll
            for (int rg = 0; rg < 4; ++rg) {
                int node = nid[r0 + m * 16 + quad * 4 + rg];
                if (node >= 0)
                    out[(size_t)node * DIM + c * 16 + l16] =
                        acc[m][c][rg] * sig;
            }
}

extern "C" void kernel_launch(void* const* d_in, const int* in_sizes, int n_in,
                              void* d_out, int out_size, void* d_ws,
                              size_t ws_size, hipStream_t stream) {
    const float* h = (const float*)d_in[0];
    const int* adj = (const int*)d_in[1];
    const int* etype = (const int*)d_in[2];
    const int* ntype = (const int*)d_in[3];
    const float* Wk = (const float*)d_in[6];
    const float* Wq = (const float*)d_in[7];
    const float* Wv = (const float*)d_in[8];
    const float* Wa = (const float*)d_in[9];
    const float* pri = (const float*)d_in[10];
    const float* att = (const float*)d_in[11];
    const float* msg = (const float*)d_in[12];
    const float* skip = (const float*)d_in[13];
    float* out = (float*)d_out;

    int* wsi = (int*)d_ws + OFF_INT;
    _Float16* wsh = (_Float16*)d_ws;
    _Float16* UF = wsh + (size_t)OFF_U * 2;
    _Float16* hF = wsh + (size_t)OFF_HF * 2;
    _Float16* VMF = wsh + (size_t)OFF_VM * 2;
    _Float16* qF = wsh + (size_t)OFF_QF * 2;
    _Float16* kF = wsh + (size_t)OFF_KF * 2;
    _Float16* aggF = wsh + (size_t)OFF_AGGF * 2;
    _Float16* vF = wsh + (size_t)OFF_VF * 2;
    _Float16* attF = wsh + (size_t)OFF_ATTF * 2;
    _Float16* msgT = wsh + (size_t)OFF_MSGT * 2;
    _Float16* WvT = wsh + (size_t)OFF_WVT * 2;
    _Float16* WaT = wsh + (size_t)OFF_WAT * 2;

    init_kernel<<<(100000 + 255) / 256, 256, 0, stream>>>(wsi);
    convert_kernel<<<(RR * DIM * DIM + 255) / 256, 256, 0, stream>>>(
        att, msg, Wv, Wa, attF, msgT, WvT, WaT);
    hconv_kernel<<<(N_NODES * DIM / 4 + 255) / 256, 256, 0, stream>>>(h, hF);
    hist_kernel<<<GRID_E, 256, 0, stream>>>(ntype, adj, wsi);
    offsets_kernel<<<1, 1, 0, stream>>>(wsi);
    scanA_kernel<<<SCAN_BLOCKS, 256, 0, stream>>>(wsi);
    scanB_kernel<<<1, 256, 0, stream>>>(wsi);
    scanC_kernel<<<SCAN_BLOCKS, 256, 0, stream>>>(wsi);
    scatter_kernel<<<GRID_E, 256, 0, stream>>>(ntype, etype, adj, wsi);
    kq_f32_kernel<<<CHUNK_GRID * 4, 256, 0, stream>>>(h, ntype, Wk, Wq,
                                                      wsi + IO_NLIST, kF, qF);
    vproj_kernel<<<CHUNK_GRID, 256, 0, stream>>>(hF, ntype, WvT,
                                                 wsi + IO_NLIST, vF);
    {
        dim3 g(GEMM_ROWBLKS, 2);
        nr_gemm2_kernel<<<g, 256, 0, stream>>>(qF, attF, UF, vF, msgT, VMF,
                                               pri);
    }
    attend_kernel<<<(N_NODES + 3) / 4, 256, 0, stream>>>(
        kF, UF, VMF, wsi + IO_DPR, wsi + IO_DOFF, wsi + IO_DCNT, aggF);
    out_kernel<<<CHUNK_GRID, 256, 0, stream>>>(aggF, ntype, WaT, skip,
                                               wsi + IO_NLIST, out);
}